// Round 11
// baseline (7923.717 us; speedup 1.0000x reference)
//
#include <hip/hip_runtime.h>
#include <math.h>

// NeuroRNN: I = 0.8 I + 0.2 (Wrec r + Win x_t); r = 0.9 r + 0.1 tanh(I); out = Wout r
// B=32, T=2048, IN=256, H=1024, OUT=128 (all fp32)
//
// R11 = R9 (best) + TWO-STREAM LATENCY HIDING. 16 groups x 2 batches; WG
// (P=blk&7, jb=blk>>3) serves groups gA=P, gB=P+8 with SHARED bf16 Wrec
// A-fragments (128 VGPRs). Per step: phase A then phase B; each phase's MALL
// handoff (publish->visible + poll) overlaps the other phase's compute.
// Exchange protocol unchanged from R7-R9 (proven): self-validating bf16 r,
// dword-LSB step tag, sc0 sc1 MALL loads/stores, fire-and-forget publish.
// Split poll: next phase's sweep issued (asm) before shadow work; finished
// with register-tied vmcnt(0). x prefetched one phase ahead, issued right
// after the barrier (so barrier drains never eat cold-x latency).

#define T_STEPS 2048
#define IN_SZ 256
#define H_SZ 1024
#define OUT_SZ 128
#define WGS 256
#define NWG 256
#define PB_WORDS 16384                 // dwords per dbuf half: 16 grp x 1024
#define WS_WORDS (2 * PB_WORDS)

typedef unsigned int u32;
typedef u32 u32x2 __attribute__((ext_vector_type(2)));
typedef u32 u32x4 __attribute__((ext_vector_type(4)));
typedef float f32x4 __attribute__((ext_vector_type(4)));
typedef short s16x8 __attribute__((ext_vector_type(8)));

// init: tag bit = 1 (expected tag for "step -1"), bf16 halves ~= 0
__global__ void nrnn_init_ws(u32* __restrict__ ws) {
  const int i = blockIdx.x * blockDim.x + threadIdx.x;
  if (i < WS_WORDS) ws[i] = 0x00000001u;
}

__device__ __forceinline__ u32 bf16r(float v) {
  const u32 b = __float_as_uint(v);
  return (b + 0x7FFFu + ((b >> 16) & 1u)) >> 16;
}
__device__ __forceinline__ float tanh_fast(float v) {
  const float cx = fminf(fmaxf(v, -15.f), 15.f);
  const float e = __expf(2.f * cx);
  return (e - 1.f) * __builtin_amdgcn_rcpf(e + 1.f);
}

#define SWEEP_RETRY(dst, ptr, etg)                                            \
  for (;;) {                                                                  \
    u32 bad_ = 0;                                                             \
    bad_ |= (dst)[0] ^ (etg); bad_ |= (dst)[1] ^ (etg);                       \
    bad_ |= (dst)[2] ^ (etg); bad_ |= (dst)[3] ^ (etg);                       \
    if (!__any(bad_ & 1u)) break;                                             \
    asm volatile("global_load_dwordx4 %0, %1, off sc0 sc1\n\t"                \
                 "s_waitcnt vmcnt(0)"                                         \
                 : "=&v"(dst) : "v"(ptr) : "memory");                         \
  }

// One phase: finish sweep for (GS,G) -> stage -> barrier -> issue x for
// (ISSG, ISST) -> MFMA -> publish (IST,RL) -> out -> issue next sweep
// (NXTG, buffer NXTB) into SWNXT -> winx(XVC) for group OGS at t+1.
#define PHASE(GS, G, OGS, t, SWCUR, SWNXT, NXTG, NXTB, IST, RL, XVI, ISSG, ISST, XVC) \
  do {                                                                        \
    const u32 etag_ = (((u32)((t) - 1)) >> 1) & 1u;                           \
    const u32* sp_ = pbuf + (size_t)(((t) + 1) & 1) * PB_WORDS                \
                     + (size_t)(G) * 1024 + 4 * tid;                          \
    asm volatile("s_waitcnt vmcnt(0)" : "+v"(SWCUR) :: "memory");             \
    SWEEP_RETRY(SWCUR, sp_, etag_);                                           \
    {                                                                         \
      const int byte0_ = 16 * tid;                                            \
      const int swz_ = ((byte0_ >> 11) & 1) << 6;                             \
      *(u32x4*)(&r_lds[GS][(t) & 1][0] + (byte0_ ^ swz_)) = SWCUR;            \
    }                                                                         \
    __syncthreads();                                                          \
    {                                                                         \
      const int it_ = (ISST) < T_STEPS ? (ISST) : (T_STEPS - 1);              \
      ldx((ISSG), it_, XVI);                                                  \
    }                                                                         \
    f32x4 acc_ = {0.f, 0.f, 0.f, 0.f};                                        \
    if (wv <= 2) {                                                            \
      const int beff_ = ln & 1;                                               \
      const int g16_ = ((ln >> 4) & 3) * 16;                                  \
      const char* rb_ = &r_lds[GS][(t) & 1][0] + beff_ * 2048;                \
      _Pragma("unroll")                                                       \
      for (int st_ = 0; st_ < 32; ++st_) {                                    \
        const s16x8 bf_ =                                                     \
            *(const s16x8*)(rb_ + ((st_ * 64 + g16_) ^ (beff_ << 6)));        \
        acc_ = __builtin_amdgcn_mfma_f32_16x16x32_bf16(wfrag[st_], bf_,       \
                                                       acc_, 0, 0, 0);        \
      }                                                                       \
    }                                                                         \
    if (wv < 2 && (ln & 14) == 0) {                                           \
      const int b_ = ln & 1, g4_ = ln >> 4;                                   \
      const int rbase_ = wv * 16 + g4_ * 4;                                   \
      const u32 ptag_ = (((u32)(t)) >> 1) & 1u;                               \
      const float I0_ =                                                       \
          fmaf(0.2f, acc_[0] + wacc_lds[GS][(t) & 1][rbase_ + 0][b_],         \
               0.8f * IST[0]);                                                \
      const float I1_ =                                                       \
          fmaf(0.2f, acc_[1] + wacc_lds[GS][(t) & 1][rbase_ + 1][b_],         \
               0.8f * IST[1]);                                                \
      const float I2_ =                                                       \
          fmaf(0.2f, acc_[2] + wacc_lds[GS][(t) & 1][rbase_ + 2][b_],         \
               0.8f * IST[2]);                                                \
      const float I3_ =                                                       \
          fmaf(0.2f, acc_[3] + wacc_lds[GS][(t) & 1][rbase_ + 3][b_],         \
               0.8f * IST[3]);                                                \
      IST[0] = I0_; IST[1] = I1_; IST[2] = I2_; IST[3] = I3_;                 \
      RL[0] = fmaf(0.1f, tanh_fast(I0_), 0.9f * RL[0]);                       \
      RL[1] = fmaf(0.1f, tanh_fast(I1_), 0.9f * RL[1]);                       \
      RL[2] = fmaf(0.1f, tanh_fast(I2_), 0.9f * RL[2]);                       \
      RL[3] = fmaf(0.1f, tanh_fast(I3_), 0.9f * RL[3]);                       \
      u32x2 pk_;                                                              \
      pk_[0] = (((bf16r(RL[1]) << 16) | (bf16r(RL[0]) & 0xFFFFu)) & ~1u) |    \
               ptag_;                                                         \
      pk_[1] = (((bf16r(RL[3]) << 16) | (bf16r(RL[2]) & 0xFFFFu)) & ~1u) |    \
               ptag_;                                                         \
      u32* pw_ = pbuf + (size_t)((t) & 1) * PB_WORDS + (size_t)(G) * 1024 +   \
                 b_ * 512 + (jb * 16 + wv * 8 + g4_ * 2);                     \
      asm volatile("global_store_dwordx2 %0, %1, off sc0 sc1"                 \
                   :: "v"(pw_), "v"(pk_) : "memory");                         \
    }                                                                         \
    if (wv == 2 && ln < 2 && (t) > 0) {                                       \
      _Pragma("unroll")                                                       \
      for (int r_ = 0; r_ < 4; ++r_)                                          \
        out[((size_t)(2 * (G) + ln) * T_STEPS + (size_t)((t) - 1)) * OUT_SZ + \
            jb * 4 + r_] = acc_[r_];                                          \
    }                                                                         \
    {                                                                         \
      const u32* np_ = pbuf + (size_t)(NXTB) * PB_WORDS +                     \
                       (size_t)(NXTG) * 1024 + 4 * tid;                       \
      asm volatile("global_load_dwordx4 %0, %1, off sc0 sc1"                  \
                   : "=v"(SWNXT) : "v"(np_) : "memory");                      \
    }                                                                         \
    winx(XVC, &wacc_lds[OGS][((t) + 1) & 1][0]);                              \
  } while (0)

__global__ void __launch_bounds__(WGS, 1)
nrnn_main(const float* __restrict__ x, const float* __restrict__ Win,
          const float* __restrict__ Wrec, const float* __restrict__ Wout,
          float* __restrict__ out, float* __restrict__ ws) {
  const int tid = (int)threadIdx.x;
  const int hg  = tid >> 5;   // 0..7 : h sub-group for Win*x (4 rows each)
  const int s   = tid & 31;   // 0..31: k-slice lane for Win*x
  const int wv  = tid >> 6;   // wave: 0,1 = Wrec-MFMA; 2 = Wout-MFMA; 3 = aux
  const int ln  = tid & 63;   // lane in wave
  const int P   = (int)blockIdx.x & 7;
  const int jb  = (int)blockIdx.x >> 3;  // h-slice [32jb, 32jb+32)
  const int gA = P, gB = P + 8;          // two groups; group g = batches {2g,2g+1}

  u32* pbuf = (u32*)ws;

  __shared__ __align__(16) char r_lds[2][2][4096];  // [slot][dbuf][2 x 2KB], swz
  __shared__ float wacc_lds[2][2][32][2];           // [slot][dbuf][row][batch]

  // ---- A-fragments -> VGPRs (static bf16 weights; SHARED by both groups) ----
  s16x8 wfrag[32];
  {
    const int g = (ln >> 4) & 3;
    const float* wp;
    if (wv < 2)       wp = Wrec + (size_t)(jb * 32 + wv * 16 + (ln & 15)) * H_SZ;
    else if (wv == 2) wp = Wout + (size_t)(jb * 4 + (ln & 3)) * H_SZ;
    else              wp = Wrec;  // wave 3: content unused
    #pragma unroll
    for (int st = 0; st < 32; ++st) {
      const int k0 = st * 32 + g * 8;
      const float4 c0 = *(const float4*)(wp + k0);
      const float4 c1 = *(const float4*)(wp + k0 + 4);
      s16x8 w;
      w[0] = (short)bf16r(c0.x); w[1] = (short)bf16r(c0.y);
      w[2] = (short)bf16r(c0.z); w[3] = (short)bf16r(c0.w);
      w[4] = (short)bf16r(c1.x); w[5] = (short)bf16r(c1.y);
      w[6] = (short)bf16r(c1.z); w[7] = (short)bf16r(c1.w);
      wfrag[st] = w;
    }
  }

  // ---- Win slice -> registers (fp32) ----
  float4 wi4[4][2];
  #pragma unroll
  for (int hh = 0; hh < 4; ++hh) {
    const float* ip = Win + (size_t)(jb * 32 + hg * 4 + hh) * IN_SZ + s * 4;
    wi4[hh][0] = *(const float4*)(ip);
    wi4[hh][1] = *(const float4*)(ip + 128);
  }

  // ---- x loader + Win*x (2 batches) ----
  auto ldx = [&](int G, int tt, float4 (&xv)[2][2]) {
    #pragma unroll
    for (int b2 = 0; b2 < 2; ++b2) {
      const float* xp = x + ((size_t)(2 * G + b2) * T_STEPS + (size_t)tt) * IN_SZ + s * 4;
      xv[b2][0] = *(const float4*)(xp);
      xv[b2][1] = *(const float4*)(xp + 128);
    }
  };
  auto winx = [&](const float4 (&xv)[2][2], float (*dst)[2]) {
    float wa[2][4];
    #pragma unroll
    for (int b2 = 0; b2 < 2; ++b2)
      #pragma unroll
      for (int hh = 0; hh < 4; ++hh) wa[b2][hh] = 0.f;
    #pragma unroll
    for (int b2 = 0; b2 < 2; ++b2) {
      const float4 x0 = xv[b2][0];
      const float4 x1 = xv[b2][1];
      #pragma unroll
      for (int hh = 0; hh < 4; ++hh) {
        float4 w4 = wi4[hh][0];
        wa[b2][hh] = fmaf(w4.x, x0.x, wa[b2][hh]);
        wa[b2][hh] = fmaf(w4.y, x0.y, wa[b2][hh]);
        wa[b2][hh] = fmaf(w4.z, x0.z, wa[b2][hh]);
        wa[b2][hh] = fmaf(w4.w, x0.w, wa[b2][hh]);
        w4 = wi4[hh][1];
        wa[b2][hh] = fmaf(w4.x, x1.x, wa[b2][hh]);
        wa[b2][hh] = fmaf(w4.y, x1.y, wa[b2][hh]);
        wa[b2][hh] = fmaf(w4.z, x1.z, wa[b2][hh]);
        wa[b2][hh] = fmaf(w4.w, x1.w, wa[b2][hh]);
      }
    }
    #pragma unroll
    for (int m = 1; m <= 16; m <<= 1)
      #pragma unroll
      for (int b2 = 0; b2 < 2; ++b2)
        #pragma unroll
        for (int hh = 0; hh < 4; ++hh)
          wa[b2][hh] += __shfl_xor(wa[b2][hh], m, 64);
    if (s < 8) dst[hg * 4 + (s & 3)][s >> 2] = wa[s >> 2][s & 3];
  };

  // ---- persistent per-group state (publishing lanes) ----
  float IstA[4] = {0.f, 0.f, 0.f, 0.f}, rlA[4] = {0.f, 0.f, 0.f, 0.f};
  float IstB[4] = {0.f, 0.f, 0.f, 0.f}, rlB[4] = {0.f, 0.f, 0.f, 0.f};

  // ---- prologue: WinX for t=0 (sync), x_B(1) prefetch, first sweep issue ----
  float4 xvA[2][2], xvB[2][2];
  {
    float4 x0A[2][2], x0B[2][2];
    ldx(gA, 0, x0A);
    ldx(gB, 0, x0B);
    winx(x0A, &wacc_lds[0][0][0]);
    winx(x0B, &wacc_lds[1][0][0]);
  }
  ldx(gB, 1, xvB);  // consumed by phase A(0)'s winx (WinX_B(1))
  u32x4 swA, swB;
  {
    const u32* p0 = pbuf + (size_t)PB_WORDS + (size_t)gA * 1024 + 4 * tid;
    asm volatile("global_load_dwordx4 %0, %1, off sc0 sc1"
                 : "=v"(swA) : "v"(p0) : "memory");
  }
  __syncthreads();  // wacc_lds[..][0] visible before phase A(0) reads it

  for (int t = 0; t < T_STEPS; ++t) {
    // phase A: group gA; issues x_A(t+1) (for phase B's winx); next sweep = B(t)
    PHASE(0, gA, 1, t, swA, swB, gB, (t + 1) & 1, IstA, rlA,
          xvA, gA, t + 1, xvB);
    // phase B: group gB; issues x_B(t+2) (for phase A(t+1)); next sweep = A(t+1)
    PHASE(1, gB, 0, t, swB, swA, gA, t & 1, IstB, rlB,
          xvB, gB, t + 2, xvA);
  }

  // ---- epilogue: out(T-1) for both groups (r published at t=T-1, buffer 1) ----
  const u32 etagF = (((u32)(T_STEPS - 1)) >> 1) & 1u;
  {
    const u32* sp = pbuf + (size_t)PB_WORDS + (size_t)gA * 1024 + 4 * tid;
    asm volatile("s_waitcnt vmcnt(0)" : "+v"(swA) :: "memory");
    SWEEP_RETRY(swA, sp, etagF);
    const int byte0 = 16 * tid;
    *(u32x4*)(&r_lds[0][0][0] + (byte0 ^ (((byte0 >> 11) & 1) << 6))) = swA;
  }
  __syncthreads();
  if (wv == 2) {
    f32x4 acc = {0.f, 0.f, 0.f, 0.f};
    const int beff = ln & 1;
    const int g16 = ((ln >> 4) & 3) * 16;
    const char* rb = &r_lds[0][0][0] + beff * 2048;
    #pragma unroll
    for (int st = 0; st < 32; ++st) {
      const s16x8 bf = *(const s16x8*)(rb + ((st * 64 + g16) ^ (beff << 6)));
      acc = __builtin_amdgcn_mfma_f32_16x16x32_bf16(wfrag[st], bf, acc, 0, 0, 0);
    }
    if (ln < 2) {
      #pragma unroll
      for (int r = 0; r < 4; ++r)
        out[((size_t)(2 * gA + ln) * T_STEPS + (size_t)(T_STEPS - 1)) * OUT_SZ +
            jb * 4 + r] = acc[r];
    }
  }
  {
    const u32* sp = pbuf + (size_t)PB_WORDS + (size_t)gB * 1024 + 4 * tid;
    asm volatile("global_load_dwordx4 %0, %1, off sc0 sc1\n\t"
                 "s_waitcnt vmcnt(0)"
                 : "=&v"(swB) : "v"(sp) : "memory");
    SWEEP_RETRY(swB, sp, etagF);
    const int byte0 = 16 * tid;
    *(u32x4*)(&r_lds[1][0][0] + (byte0 ^ (((byte0 >> 11) & 1) << 6))) = swB;
  }
  __syncthreads();
  if (wv == 2) {
    f32x4 acc = {0.f, 0.f, 0.f, 0.f};
    const int beff = ln & 1;
    const int g16 = ((ln >> 4) & 3) * 16;
    const char* rb = &r_lds[1][0][0] + beff * 2048;
    #pragma unroll
    for (int st = 0; st < 32; ++st) {
      const s16x8 bf = *(const s16x8*)(rb + ((st * 64 + g16) ^ (beff << 6)));
      acc = __builtin_amdgcn_mfma_f32_16x16x32_bf16(wfrag[st], bf, acc, 0, 0, 0);
    }
    if (ln < 2) {
      #pragma unroll
      for (int r = 0; r < 4; ++r)
        out[((size_t)(2 * gB + ln) * T_STEPS + (size_t)(T_STEPS - 1)) * OUT_SZ +
            jb * 4 + r] = acc[r];
    }
  }
}

extern "C" void kernel_launch(void* const* d_in, const int* in_sizes, int n_in,
                              void* d_out, int out_size, void* d_ws, size_t ws_size,
                              hipStream_t stream) {
  const float* xp    = (const float*)d_in[0];
  const float* winp  = (const float*)d_in[1];
  const float* wrecp = (const float*)d_in[2];
  const float* woutp = (const float*)d_in[3];
  float* outp = (float*)d_out;
  float* wsp  = (float*)d_ws;

  // re-init packed r buffers to tag=1 / value~0 every call (graph-replay safe)
  nrnn_init_ws<<<(WS_WORDS + 255) / 256, 256, 0, stream>>>((u32*)d_ws);

  nrnn_main<<<dim3(NWG), dim3(WGS), 0, stream>>>(xp, winp, wrecp, woutp, outp, wsp);
}

// Round 12
// 5505.264 us; speedup vs baseline: 1.4393x; 1.4393x over previous
//
#include <hip/hip_runtime.h>
#include <math.h>

// NeuroRNN: I = 0.8 I + 0.2 (Wrec r + Win x_t); r = 0.9 r + 0.1 tanh(I); out = Wout r
// B=32, T=2048, IN=256, H=1024, OUT=128 (all fp32)
//
// R12 = R9 skeleton (best, 6.09 ms) with the fixed per-step cost removed:
//  - Win*x on matrix cores: waves 0,1 hold 8 static bf16 Win A-frags; x packed
//    to bf16 via v_perm and fed as B-frags; 8 MFMAs replace 128 scalar FMA +
//    80 shuffle-reduce + wacc_lds round trip. Win-MFMA C layout lands on the
//    exact lanes/regs that do the I-update.
//  - Pre-issued sweep (R11-validated): t+1's tagged r loads issued at end of
//    step t; finished with register-tied vmcnt(0). Tag protocol rejects
//    stale/future data (tags of t and t+2 always differ) -> no deadlock.
//  - Dual-chain MFMA accumulators; float4 out store.
// Exchange protocol unchanged from R7-R9 (proven): self-validating bf16 r,
// dword-LSB step tag, sc0 sc1 MALL loads/stores, fire-and-forget publish.

#define T_STEPS 2048
#define IN_SZ 256
#define H_SZ 1024
#define OUT_SZ 128
#define WGS 256
#define NWG 256
#define PB_WORDS 16384                 // dwords per dbuf half: 32 batch x 512
#define WS_WORDS (2 * PB_WORDS)

typedef unsigned int u32;
typedef u32 u32x2 __attribute__((ext_vector_type(2)));
typedef u32 u32x4 __attribute__((ext_vector_type(4)));
typedef float f32x4 __attribute__((ext_vector_type(4)));
typedef short s16x8 __attribute__((ext_vector_type(8)));

// init: tag bit = 1 (expected tag for "step -1"), bf16 halves ~= 0
__global__ void nrnn_init_ws(u32* __restrict__ ws) {
  const int i = blockIdx.x * blockDim.x + threadIdx.x;
  if (i < WS_WORDS) ws[i] = 0x00000001u;
}

__device__ __forceinline__ u32 bf16r(float v) {  // round-to-nearest-even bf16
  const u32 b = __float_as_uint(v);
  return (b + 0x7FFFu + ((b >> 16) & 1u)) >> 16;
}
__device__ __forceinline__ float tanh_fast(float v) {
  const float cx = fminf(fmaxf(v, -15.f), 15.f);
  const float e = __expf(2.f * cx);
  return (e - 1.f) * __builtin_amdgcn_rcpf(e + 1.f);
}

__global__ void __launch_bounds__(WGS, 1)
nrnn_main(const float* __restrict__ x, const float* __restrict__ Win,
          const float* __restrict__ Wrec, const float* __restrict__ Wout,
          float* __restrict__ out, float* __restrict__ ws) {
  const int tid = (int)threadIdx.x;
  const int wv  = tid >> 6;   // wave: 0,1 = Wrec+Win MFMA; 2 = Wout MFMA; 3 = aux
  const int ln  = tid & 63;   // lane in wave
  const int bg  = (int)blockIdx.x & 7;   // batch group (batches [4bg,4bg+4))
  const int jb  = (int)blockIdx.x >> 3;  // h-slice [32jb, 32jb+32)
  const int b0  = bg * 4;

  u32* pbuf = (u32*)ws;
  __shared__ __align__(16) char r_lds[8192];  // bf16 r [4 batch][1024 k], swizzled

  // ---- Wrec/Wout A-fragments -> VGPRs (static bf16, R9-proven layout) ----
  s16x8 wfrag[32];
  {
    const int g = (ln >> 4) & 3;
    const float* wp;
    if (wv < 2)       wp = Wrec + (size_t)(jb * 32 + wv * 16 + (ln & 15)) * H_SZ;
    else if (wv == 2) wp = Wout + (size_t)(jb * 4 + (ln & 3)) * H_SZ;
    else              wp = Wrec;  // wave 3: content unused
    #pragma unroll
    for (int st = 0; st < 32; ++st) {
      const int k0 = st * 32 + g * 8;
      const float4 c0 = *(const float4*)(wp + k0);
      const float4 c1 = *(const float4*)(wp + k0 + 4);
      s16x8 w;
      w[0] = (short)bf16r(c0.x); w[1] = (short)bf16r(c0.y);
      w[2] = (short)bf16r(c0.z); w[3] = (short)bf16r(c0.w);
      w[4] = (short)bf16r(c1.x); w[5] = (short)bf16r(c1.y);
      w[6] = (short)bf16r(c1.z); w[7] = (short)bf16r(c1.w);
      wfrag[st] = w;
    }
  }

  // ---- Win A-fragments (waves 0,1; same rows as their Wrec rows) ----
  s16x8 wifrag[8];
  if (wv < 2) {
    const float* wp = Win + (size_t)(jb * 32 + wv * 16 + (ln & 15)) * IN_SZ
                      + ((ln >> 4) & 3) * 8;
    #pragma unroll
    for (int ch = 0; ch < 8; ++ch) {
      const float4 c0 = *(const float4*)(wp + ch * 32);
      const float4 c1 = *(const float4*)(wp + ch * 32 + 4);
      s16x8 w;
      w[0] = (short)bf16r(c0.x); w[1] = (short)bf16r(c0.y);
      w[2] = (short)bf16r(c0.z); w[3] = (short)bf16r(c0.w);
      w[4] = (short)bf16r(c1.x); w[5] = (short)bf16r(c1.y);
      w[6] = (short)bf16r(c1.z); w[7] = (short)bf16r(c1.w);
      wifrag[ch] = w;
    }
  } else {
    const s16x8 z = {0, 0, 0, 0, 0, 0, 0, 0};
    #pragma unroll
    for (int ch = 0; ch < 8; ++ch) wifrag[ch] = z;
  }

  // x loader (B-frag slots: col=batch=ln&3, k=(ln>>4)*8 within each 32-chunk)
  auto ldx_issue = [&](int tt, float4 (&xv)[16]) {
    if (wv < 2) {
      const float* xb = x + ((size_t)(b0 + (ln & 3)) * T_STEPS + (size_t)tt) * IN_SZ
                        + ((ln >> 4) & 3) * 8;
      #pragma unroll
      for (int ch = 0; ch < 8; ++ch) {
        xv[2 * ch]     = *(const float4*)(xb + ch * 32);
        xv[2 * ch + 1] = *(const float4*)(xb + ch * 32 + 4);
      }
    }
  };
  // fp32 -> packed bf16 (RTZ via v_perm: dst = hi16(a)<<16 | hi16(b))
  auto cvt = [&](const float4 (&xv)[16], u32x4 (&xf)[8]) {
    if (wv < 2) {
      #pragma unroll
      for (int ch = 0; ch < 8; ++ch) {
        u32x4 u;
        u[0] = __builtin_amdgcn_perm(__float_as_uint(xv[2 * ch].y),
                                     __float_as_uint(xv[2 * ch].x), 0x07060302u);
        u[1] = __builtin_amdgcn_perm(__float_as_uint(xv[2 * ch].w),
                                     __float_as_uint(xv[2 * ch].z), 0x07060302u);
        u[2] = __builtin_amdgcn_perm(__float_as_uint(xv[2 * ch + 1].y),
                                     __float_as_uint(xv[2 * ch + 1].x), 0x07060302u);
        u[3] = __builtin_amdgcn_perm(__float_as_uint(xv[2 * ch + 1].w),
                                     __float_as_uint(xv[2 * ch + 1].z), 0x07060302u);
        xf[ch] = u;
      }
    }
  };

  // ---- persistent state (publishing lanes of waves 0,1) ----
  float Ist[4] = {0.f, 0.f, 0.f, 0.f};
  float rloc[4] = {0.f, 0.f, 0.f, 0.f};

  // ---- prologue: x(0) -> xf; pre-issue sweep for t=0 (buffer 1, tag 1) ----
  u32x4 xf[8];
  {
    float4 xv0[16];
    ldx_issue(0, xv0);
    cvt(xv0, xf);
  }
  u32x4 swa, swb;
  {
    const u32* sp0 = pbuf + (size_t)PB_WORDS + (size_t)bg * 2048 + 4 * tid;
    asm volatile("global_load_dwordx4 %0, %2, off sc0 sc1\n\t"
                 "global_load_dwordx4 %1, %3, off sc0 sc1"
                 : "=v"(swa), "=v"(swb) : "v"(sp0), "v"(sp0 + 1024) : "memory");
  }

  for (int t = 0; t < T_STEPS; ++t) {
    // ---- finish pre-issued sweep; retry until all tags match ----
    const u32 etag = (((u32)(t - 1)) >> 1) & 1u;
    const u32* sp0 = pbuf + (size_t)((t + 1) & 1) * PB_WORDS + (size_t)bg * 2048 + 4 * tid;
    asm volatile("s_waitcnt vmcnt(0)" : "+v"(swa), "+v"(swb) :: "memory");
    for (;;) {
      u32 bad = 0;
      #pragma unroll
      for (int i = 0; i < 4; ++i) { bad |= swa[i] ^ etag; bad |= swb[i] ^ etag; }
      if (!__any(bad & 1u)) break;
      asm volatile("global_load_dwordx4 %0, %2, off sc0 sc1\n\t"
                   "global_load_dwordx4 %1, %3, off sc0 sc1\n\t"
                   "s_waitcnt vmcnt(0)"
                   : "=&v"(swa), "=&v"(swb) : "v"(sp0), "v"(sp0 + 1024) : "memory");
    }
    // ---- stage to swizzled LDS (R9-proven, conflict-free) ----
    {
      const int bi0 = tid >> 7, bi1 = 2 + bi0;
      *(u32x4*)(r_lds + ((16 * tid) ^ ((bi0 & 3) << 4) ^ ((bi0 & 1) << 6))) = swa;
      *(u32x4*)(r_lds + ((4096 + 16 * tid) ^ ((bi1 & 3) << 4) ^ ((bi1 & 1) << 6))) = swb;
    }
    __syncthreads();  // bar A: r_lds ready

    // ---- issue x(t+1) loads (latency hides under MFMA/publish below) ----
    float4 xv[16];
    ldx_issue((t + 1 < T_STEPS) ? t + 1 : t, xv);

    // ---- Wrec / Wout MFMA over K=1024, dual accumulator chains ----
    f32x4 acc = {0.f, 0.f, 0.f, 0.f};
    if (wv <= 2) {
      const int beff = ln & 3;
      const int g16 = ((ln >> 4) & 3) * 16;
      const int bswz = ((beff & 3) << 4) | ((beff & 1) << 6);
      const char* rb = r_lds + beff * 2048;
      f32x4 a0 = {0.f, 0.f, 0.f, 0.f}, a1 = {0.f, 0.f, 0.f, 0.f};
      #pragma unroll
      for (int st = 0; st < 32; st += 2) {
        const s16x8 bfa = *(const s16x8*)(rb + ((st * 64 + g16) ^ bswz));
        const s16x8 bfb = *(const s16x8*)(rb + (((st + 1) * 64 + g16) ^ bswz));
        a0 = __builtin_amdgcn_mfma_f32_16x16x32_bf16(wfrag[st], bfa, a0, 0, 0, 0);
        a1 = __builtin_amdgcn_mfma_f32_16x16x32_bf16(wfrag[st + 1], bfb, a1, 0, 0, 0);
      }
      acc = a0 + a1;
    }

    // ---- Win*x via MFMA (waves 0,1; same C layout as acc) ----
    f32x4 wm = {0.f, 0.f, 0.f, 0.f};
    if (wv < 2) {
      #pragma unroll
      for (int ch = 0; ch < 8; ++ch)
        wm = __builtin_amdgcn_mfma_f32_16x16x32_bf16(wifrag[ch],
                                                     *(const s16x8*)&xf[ch], wm, 0, 0, 0);
    }

    // ---- I update; tanh; tagged bf16 publish (fire-and-forget dwordx2) ----
    if (wv < 2 && (ln & 12) == 0) {
      const int b = ln & 3, g4 = ln >> 4;
      const u32 ptag = (((u32)t) >> 1) & 1u;
      const float I0 = fmaf(0.2f, acc[0] + wm[0], 0.8f * Ist[0]);
      const float I1 = fmaf(0.2f, acc[1] + wm[1], 0.8f * Ist[1]);
      const float I2 = fmaf(0.2f, acc[2] + wm[2], 0.8f * Ist[2]);
      const float I3 = fmaf(0.2f, acc[3] + wm[3], 0.8f * Ist[3]);
      Ist[0] = I0; Ist[1] = I1; Ist[2] = I2; Ist[3] = I3;
      rloc[0] = fmaf(0.1f, tanh_fast(I0), 0.9f * rloc[0]);
      rloc[1] = fmaf(0.1f, tanh_fast(I1), 0.9f * rloc[1]);
      rloc[2] = fmaf(0.1f, tanh_fast(I2), 0.9f * rloc[2]);
      rloc[3] = fmaf(0.1f, tanh_fast(I3), 0.9f * rloc[3]);
      u32x2 pk;
      pk[0] = (((bf16r(rloc[1]) << 16) | (bf16r(rloc[0]) & 0xFFFFu)) & ~1u) | ptag;
      pk[1] = (((bf16r(rloc[3]) << 16) | (bf16r(rloc[2]) & 0xFFFFu)) & ~1u) | ptag;
      u32* pw = pbuf + (size_t)(t & 1) * PB_WORDS + (size_t)(b0 + b) * 512
                + jb * 16 + wv * 8 + g4 * 2;
      asm volatile("global_store_dwordx2 %0, %1, off sc0 sc1"
                   :: "v"(pw), "v"(pk) : "memory");
    }

    // ---- wave 2: out_{t-1} = Wout r_{t-1} (one float4 store) ----
    if (wv == 2 && ln < 4 && t > 0) {
      float4 o; o.x = acc[0]; o.y = acc[1]; o.z = acc[2]; o.w = acc[3];
      *(float4*)(out + ((size_t)(b0 + ln) * T_STEPS + (size_t)(t - 1)) * OUT_SZ
                 + jb * 4) = o;
    }

    // ---- convert x(t+1) -> xf (x loads land under the work above) ----
    cvt(xv, xf);

    // ---- pre-issue sweep for t+1 (buffer t&1) ----
    {
      const u32* np0 = pbuf + (size_t)(t & 1) * PB_WORDS + (size_t)bg * 2048 + 4 * tid;
      asm volatile("global_load_dwordx4 %0, %2, off sc0 sc1\n\t"
                   "global_load_dwordx4 %1, %3, off sc0 sc1"
                   : "=v"(swa), "=v"(swb) : "v"(np0), "v"(np0 + 1024) : "memory");
    }
    __syncthreads();  // bar B: all waves done with r_lds before next stage
  }

  // ---- epilogue: out(T-1); pre-issued sweep targets buffer 1, etag 1 ----
  {
    const u32 etag = (((u32)(T_STEPS - 1)) >> 1) & 1u;
    const u32* sp0 = pbuf + (size_t)PB_WORDS + (size_t)bg * 2048 + 4 * tid;
    asm volatile("s_waitcnt vmcnt(0)" : "+v"(swa), "+v"(swb) :: "memory");
    for (;;) {
      u32 bad = 0;
      #pragma unroll
      for (int i = 0; i < 4; ++i) { bad |= swa[i] ^ etag; bad |= swb[i] ^ etag; }
      if (!__any(bad & 1u)) break;
      asm volatile("global_load_dwordx4 %0, %2, off sc0 sc1\n\t"
                   "global_load_dwordx4 %1, %3, off sc0 sc1\n\t"
                   "s_waitcnt vmcnt(0)"
                   : "=&v"(swa), "=&v"(swb) : "v"(sp0), "v"(sp0 + 1024) : "memory");
    }
    const int bi0 = tid >> 7, bi1 = 2 + bi0;
    *(u32x4*)(r_lds + ((16 * tid) ^ ((bi0 & 3) << 4) ^ ((bi0 & 1) << 6))) = swa;
    *(u32x4*)(r_lds + ((4096 + 16 * tid) ^ ((bi1 & 3) << 4) ^ ((bi1 & 1) << 6))) = swb;
  }
  __syncthreads();
  if (wv == 2) {
    const int beff = ln & 3;
    const int g16 = ((ln >> 4) & 3) * 16;
    const int bswz = ((beff & 3) << 4) | ((beff & 1) << 6);
    const char* rb = r_lds + beff * 2048;
    f32x4 acc = {0.f, 0.f, 0.f, 0.f};
    #pragma unroll
    for (int st = 0; st < 32; ++st) {
      const s16x8 bf = *(const s16x8*)(rb + ((st * 64 + g16) ^ bswz));
      acc = __builtin_amdgcn_mfma_f32_16x16x32_bf16(wfrag[st], bf, acc, 0, 0, 0);
    }
    if (ln < 4) {
      float4 o; o.x = acc[0]; o.y = acc[1]; o.z = acc[2]; o.w = acc[3];
      *(float4*)(out + ((size_t)(b0 + ln) * T_STEPS + (size_t)(T_STEPS - 1)) * OUT_SZ
                 + jb * 4) = o;
    }
  }
}

extern "C" void kernel_launch(void* const* d_in, const int* in_sizes, int n_in,
                              void* d_out, int out_size, void* d_ws, size_t ws_size,
                              hipStream_t stream) {
  const float* xp    = (const float*)d_in[0];
  const float* winp  = (const float*)d_in[1];
  const float* wrecp = (const float*)d_in[2];
  const float* woutp = (const float*)d_in[3];
  float* outp = (float*)d_out;
  float* wsp  = (float*)d_ws;

  // re-init packed r buffers to tag=1 / value~0 every call (graph-replay safe)
  nrnn_init_ws<<<(WS_WORDS + 255) / 256, 256, 0, stream>>>((u32*)d_ws);

  nrnn_main<<<dim3(NWG), dim3(WGS), 0, stream>>>(xp, winp, wrecp, woutp, outp, wsp);
}